// Round 15
// baseline (89.837 us; speedup 1.0000x reference)
//
#include <hip/hip_runtime.h>

// phi (B,2,H,W) f32 -> out (B,1,H,W) f32 ; splat ones with bilinear weights, wrap BC.
// Gather formulation, RB=8 multi-row amortization, store-only commit, pruned (t,m).
// R15: f16x2-PACKED col tents + rank-1 slot accumulate (v_pk_*_f16 is full-rate on
// CDNA4 = 2 ops/issue; VOP3P f32 is half-rate per R10). k-dim packed as 4 pairs
// {-3,-2},{-1,0},{1,2},{3,pad}; slots accumulate in f16x2; routing extracts halves
// and sums in f32 (commit f32). Est -25..30% instruction stream vs the f32 floor
// R12-R14 plateaued at. Precision: ~2e-2 added error vs 0.12 threshold.
// Wide-displacement sources (|dx|>=3 or |dy|>=3, P~0.5%) -> per-(srow,chunk) byte
// flags (plain stores; R7/R8: contended counter == 900us wall), flushed by a second
// kernel with scattered uncontended atomics.
constexpr int H = 2048, W = 2048;
constexpr int HW = H * W;
constexpr int OUTW = 56;                    // output cols per wave (64 lanes - 8 halo)
constexpr int NCH = (W + OUTW - 1) / OUTW;  // 37 col-chunks (last ragged)
constexpr int RB  = 8;                      // owned rows per wave
constexpr int WPB = 4;                      // waves per block
constexpr int ROWSPB = RB * WPB;            // 32 rows per block
constexpr int NSRC = RB + 6;                // 14 scanned source rows per wave

typedef _Float16 f16;
typedef f16 f16x2 __attribute__((ext_vector_type(2)));

__global__ __launch_bounds__(256, 4)        // 4 waves/EU: 128-VGPR cap, ~80 live
void splat_gather8h(const float* __restrict__ phi, float* __restrict__ out,
                    unsigned char* __restrict__ flags) {
    int wid  = threadIdx.x >> 6;
    int lane = threadIdx.x & 63;

    const int rgPerImg = H / ROWSPB;        // 64
    int bid = blockIdx.x;
    int b   = bid / (NCH * rgPerImg);
    int rem = bid - b * (NCH * rgPerImg);
    int c0i = rem / rgPerImg;
    int rg  = rem - c0i * rgPerImg;
    int r0  = rg * ROWSPB + wid * RB;       // first owned row of this wave
    int c0  = c0i * OUTW;

    const float* phiB = phi + (size_t)b * 2 * HW;
    float* outb = out + (size_t)b * HW;

    int scu = c0 - 4 + lane;                // unwrapped source col of this lane
    int scw = scu & (W - 1);                // wrapped col for loads
    bool ownedCol = (lane >= 4) && (lane < 4 + OUTW) && (scu < W);

    // prefetch all candidate source rows; pins keep the 28 loads up-front & live
    float dxv[NSRC], dyv[NSRC];
    #pragma unroll
    for (int t = 0; t < NSRC; ++t) {
        int srow = (r0 + t - 3) & (H - 1);
        dxv[t] = phiB[(size_t)srow * W + scw];
        dyv[t] = phiB[(size_t)HW + (size_t)srow * W + scw];
    }
    #pragma unroll
    for (int t = 0; t < NSRC; ++t)
        asm volatile("" : "+v"(dxv[t]), "+v"(dyv[t]));

    // packed slots: per m, 4 f16x2 pairs covering col offsets {2p-3, 2p-2}
    f16x2 slot[RB][4];
    #pragma unroll
    for (int m = 0; m < RB; ++m)
        #pragma unroll
        for (int p = 0; p < 4; ++p) slot[m][p] = (f16x2)((f16)0.0);

    #pragma unroll
    for (int t = 0; t < NSRC; ++t) {
        float dx = dxv[t], dy = dyv[t];
        bool valid = (__builtin_fabsf(dx) < 3.0f) && (__builtin_fabsf(dy) < 3.0f);
        float dyM = valid ? dy : 16384.0f;   // invalid -> all col tents 0 -> flush only

        // packed col tents, once per t: ct[p] = max(1 - |dy - {2p-3,2p-2}|, 0)
        f16 dyh = (f16)dyM;
        f16x2 dy2 = {dyh, dyh};
        f16x2 ct[4];
        #pragma unroll
        for (int p = 0; p < 4; ++p) {
            const f16x2 koff = {(f16)(2 * p - 3), (f16)(2 * p - 2)};
            f16x2 d  = dy2 - koff;                       // v_pk_add (neg)
            f16x2 a  = __builtin_elementwise_abs(d);     // v_and 0x7fff7fff
            f16x2 tt = (f16x2)((f16)1.0) - a;            // v_pk_add (neg)
            ct[p] = __builtin_elementwise_max(tt, (f16x2)((f16)0.0));  // v_pk_max
        }

        // row tents (scalar f32) + packed rank-1 accumulate (pruned: t-m in [0,6])
        #pragma unroll
        for (int m = 0; m < RB; ++m) {
            if (t - m < 0 || t - m > 6) continue;        // compile-time DCE
            float dist = dx + (float)(t - 3 - m);        // x - (r0+m), unwrapped
            float rwf = __builtin_fmaxf(1.0f - __builtin_fabsf(dist), 0.0f);
            f16 rwh = (f16)rwf;
            f16x2 rw2 = {rwh, rwh};
            #pragma unroll
            for (int p = 0; p < 4; ++p)
                slot[m][p] = __builtin_elementwise_fma(rw2, ct[p], slot[m][p]);
        }

        // flag this wave's owned source rows (t in [3,3+RB)): plain byte store
        if (t >= 3 && t < 3 + RB) {
            bool need = (!valid) && ownedCol;
            unsigned long long mask = __ballot(need);
            if (lane == 0) {
                int srow = (r0 + t - 3) & (H - 1);
                flags[(size_t)(b * H + srow) * NCH + c0i] = (mask != 0ull) ? 1 : 0;
            }
        }
    }

    // route packed slots, sum in f32, commit plain stores (exclusive ownership).
    // output col (c0+lane-4) pulls: low half of pair p from lane (lane-(2p-3)),
    // high half from lane (lane-(2p-2)); p=3 high is the +4 pad (always 0) -> skip.
    #pragma unroll
    for (int m = 0; m < RB; ++m) {
        float v = 0.0f;
        #pragma unroll
        for (int p = 0; p < 4; ++p) {
            int s = __builtin_bit_cast(int, slot[m][p]);
            int rlo = __shfl(s, lane - (2 * p - 3));
            f16x2 vlo = __builtin_bit_cast(f16x2, rlo);
            v += (float)vlo.x;
            if (p < 3) {
                int rhi = __shfl(s, lane - (2 * p - 2));
                f16x2 vhi = __builtin_bit_cast(f16x2, rhi);
                v += (float)vhi.y;
            }
        }
        if (ownedCol)
            outb[(size_t)(r0 + m) * W + scu] = v;
    }
}

// Wave-batched flush: each wave reads 16 flags, processes flagged chunks (full wave each).
__global__ __launch_bounds__(256)
void flush_flagged(const float* __restrict__ phi, const unsigned char* __restrict__ flags,
                   float* __restrict__ out) {
    int wid  = threadIdx.x >> 6;
    int lane = threadIdx.x & 63;
    unsigned base = ((unsigned)blockIdx.x * WPB + (unsigned)wid) * 16u;  // 16 chunks/wave

    unsigned char f = (lane < 16) ? flags[base + (unsigned)lane] : (unsigned char)0;
    unsigned long long mask = __ballot(f != 0);

    while (mask) {
        int bit = (int)(__ffsll((long long)mask) - 1);
        mask &= mask - 1ull;
        unsigned chunk = base + (unsigned)bit;

        int c0i  = (int)(chunk % (unsigned)NCH);
        unsigned bs = chunk / (unsigned)NCH;
        int srow = (int)(bs & (H - 1));
        int b    = (int)(bs >> 11);            // H = 2048

        int col = c0i * OUTW + lane;           // lanes [0,56) own cols of this chunk
        if (lane < OUTW && col < W) {
            const float* phiB = phi + (size_t)b * 2 * HW;
            float dx = phiB[(size_t)srow * W + col];
            float dy = phiB[(size_t)HW + (size_t)srow * W + col];
            if (!((__builtin_fabsf(dx) < 3.0f) && (__builtin_fabsf(dy) < 3.0f))) {
                float* outb = out + (size_t)b * HW;
                float x = (float)srow + dx;
                float y = (float)col + dy;
                float x0 = floorf(x), y0 = floorf(y);
                float wx1 = x - x0, wx0 = 1.0f - wx1;
                float wy1 = y - y0, wy0 = 1.0f - wy1;
                int gx0 = ((int)x0) & (H - 1);
                int gx1 = (gx0 + 1) & (H - 1);
                int gy0 = ((int)y0) & (W - 1);
                int gy1 = (gy0 + 1) & (W - 1);
                atomicAdd(outb + (size_t)gx0 * W + gy0, wx0 * wy0);
                atomicAdd(outb + (size_t)gx0 * W + gy1, wx0 * wy1);
                atomicAdd(outb + (size_t)gx1 * W + gy0, wx1 * wy0);
                atomicAdd(outb + (size_t)gx1 * W + gy1, wx1 * wy1);
            }
        }
    }
}

extern "C" void kernel_launch(void* const* d_in, const int* in_sizes, int n_in,
                              void* d_out, int out_size, void* d_ws, size_t ws_size,
                              hipStream_t stream) {
    const float* phi = (const float*)d_in[0];
    float* out = (float*)d_out;
    unsigned char* flags = (unsigned char*)d_ws;   // B*H*NCH bytes, fully rewritten per call

    int B = out_size / HW;
    int grid = B * NCH * (H / ROWSPB);             // 4 * 37 * 64 = 9472 blocks
    splat_gather8h<<<grid, 256, 0, stream>>>(phi, out, flags);

    long long nChunks = (long long)B * H * NCH;    // 303,104 = 4736 * 64
    int grid2 = (int)(nChunks / (WPB * 16));       // 4736 blocks (16 chunks per wave)
    flush_flagged<<<grid2, 256, 0, stream>>>(phi, flags, out);
}

// Round 16
// 82.230 us; speedup vs baseline: 1.0925x; 1.0925x over previous
//
#include <hip/hip_runtime.h>

// phi (B,2,H,W) f32 -> out (B,1,H,W) f32 ; splat ones with bilinear weights, wrap BC.
// Gather formulation, scalar tent weights, RB=8 multi-row amortization, store-only
// commit (exclusive ownership -> no commit atomics, no output memset), compile-time-
// pruned (t,m) pairs. [BEST-MEASURED CONFIG: R14, 83.16us, absmax 0.031]
// Inline-asm "+v" pins on prefetched dx/dy and per-t col-tent vector ct[] keep the
// loads up-front and ct live (VGPR 64). Main kernel ~76us at VALUBusy ~90% ==
// f32-VALU issue-bound; f16 packing (R15) and VOP3P f32 (R10) both regressed.
// Wide-displacement sources (|dx|>=3 or |dy|>=3, P~0.5%) -> per-(srow,chunk) byte
// flags (plain stores; R7/R8: contended single-address counter == 900us wall),
// flushed by a second wave-batched kernel with scattered uncontended atomics.
constexpr int H = 2048, W = 2048;
constexpr int HW = H * W;
constexpr int OUTW = 56;                    // output cols per wave (64 lanes - 8 halo)
constexpr int NCH = (W + OUTW - 1) / OUTW;  // 37 col-chunks (last ragged)
constexpr int RB  = 8;                      // owned rows per wave
constexpr int WPB = 4;                      // waves per block
constexpr int ROWSPB = RB * WPB;            // 32 rows per block
constexpr int NSRC = RB + 6;                // 14 scanned source rows per wave

__global__ __launch_bounds__(256, 3)        // 3 waves/EU: ~170-VGPR budget
void splat_gather8o(const float* __restrict__ phi, float* __restrict__ out,
                    unsigned char* __restrict__ flags) {
    int wid  = threadIdx.x >> 6;
    int lane = threadIdx.x & 63;

    const int rgPerImg = H / ROWSPB;        // 64
    int bid = blockIdx.x;
    int b   = bid / (NCH * rgPerImg);
    int rem = bid - b * (NCH * rgPerImg);
    int c0i = rem / rgPerImg;
    int rg  = rem - c0i * rgPerImg;
    int r0  = rg * ROWSPB + wid * RB;       // first owned row of this wave
    int c0  = c0i * OUTW;

    const float* phiB = phi + (size_t)b * 2 * HW;
    float* outb = out + (size_t)b * HW;

    int scu = c0 - 4 + lane;                // unwrapped source col of this lane
    int scw = scu & (W - 1);                // wrapped col for loads
    bool ownedCol = (lane >= 4) && (lane < 4 + OUTW) && (scu < W);

    // prefetch all candidate source rows; opaque pins force completion here and
    // keep all 28 values live in VGPRs (single vmcnt exposure)
    float dxv[NSRC], dyv[NSRC];
    #pragma unroll
    for (int t = 0; t < NSRC; ++t) {
        int srow = (r0 + t - 3) & (H - 1);
        dxv[t] = phiB[(size_t)srow * W + scw];
        dyv[t] = phiB[(size_t)HW + (size_t)srow * W + scw];
    }
    #pragma unroll
    for (int t = 0; t < NSRC; ++t)
        asm volatile("" : "+v"(dxv[t]), "+v"(dyv[t]));

    float slot[RB][7];
    #pragma unroll
    for (int m = 0; m < RB; ++m)
        #pragma unroll
        for (int k = 0; k < 7; ++k) slot[m][k] = 0.0f;

    #pragma unroll
    for (int t = 0; t < NSRC; ++t) {
        float dx = dxv[t], dy = dyv[t];
        bool valid = (__builtin_fabsf(dx) < 3.0f) && (__builtin_fabsf(dy) < 3.0f);
        float dyM = valid ? dy : 16384.0f;   // invalid -> all col tents 0 -> flush only

        // scalar col tent weights toward offsets ko = k-3, computed once per t
        float ct[7];
        #pragma unroll
        for (int k = 0; k < 7; ++k) {
            float d = dyM - (float)(k - 3);
            ct[k] = __builtin_fmaxf(1.0f - __builtin_fabsf(d), 0.0f);
        }
        #pragma unroll
        for (int k = 0; k < 7; ++k)
            asm volatile("" : "+v"(ct[k]));

        // row tents toward owned rows + rank-1 accumulate (pruned: rw==0 if t-m not in [0,6])
        #pragma unroll
        for (int m = 0; m < RB; ++m) {
            if (t - m < 0 || t - m > 6) continue;   // compile-time DCE under unroll
            float dist = dx + (float)(t - 3 - m);   // x - (r0+m), unwrapped
            float rw = __builtin_fmaxf(1.0f - __builtin_fabsf(dist), 0.0f);
            #pragma unroll
            for (int k = 0; k < 7; ++k)
                slot[m][k] = __builtin_fmaf(rw, ct[k], slot[m][k]);
        }

        // flag this wave's owned source rows (t in [3,3+RB)): plain byte store, no atomics
        if (t >= 3 && t < 3 + RB) {
            bool need = (!valid) && ownedCol;
            unsigned long long mask = __ballot(need);
            if (lane == 0) {
                int srow = (r0 + t - 3) & (H - 1);
                flags[(size_t)(b * H + srow) * NCH + c0i] = (mask != 0ull) ? 1 : 0;
            }
        }
    }

    // route column slots and commit with plain stores (exclusive ownership)
    #pragma unroll
    for (int m = 0; m < RB; ++m) {
        float v = 0.0f;
        #pragma unroll
        for (int k = 0; k < 7; ++k)
            v += __shfl(slot[m][k], lane - (k - 3));
        if (ownedCol)
            outb[(size_t)(r0 + m) * W + scu] = v;
    }
}

// Wave-batched flush: each wave reads 16 flags, processes flagged chunks (full wave each).
__global__ __launch_bounds__(256)
void flush_flagged(const float* __restrict__ phi, const unsigned char* __restrict__ flags,
                   float* __restrict__ out) {
    int wid  = threadIdx.x >> 6;
    int lane = threadIdx.x & 63;
    unsigned base = ((unsigned)blockIdx.x * WPB + (unsigned)wid) * 16u;  // 16 chunks/wave

    unsigned char f = (lane < 16) ? flags[base + (unsigned)lane] : (unsigned char)0;
    unsigned long long mask = __ballot(f != 0);

    while (mask) {
        int bit = (int)(__ffsll((long long)mask) - 1);
        mask &= mask - 1ull;
        unsigned chunk = base + (unsigned)bit;

        int c0i  = (int)(chunk % (unsigned)NCH);
        unsigned bs = chunk / (unsigned)NCH;
        int srow = (int)(bs & (H - 1));
        int b    = (int)(bs >> 11);            // H = 2048

        int col = c0i * OUTW + lane;           // lanes [0,56) own cols of this chunk
        if (lane < OUTW && col < W) {
            const float* phiB = phi + (size_t)b * 2 * HW;
            float dx = phiB[(size_t)srow * W + col];
            float dy = phiB[(size_t)HW + (size_t)srow * W + col];
            if (!((__builtin_fabsf(dx) < 3.0f) && (__builtin_fabsf(dy) < 3.0f))) {
                float* outb = out + (size_t)b * HW;
                float x = (float)srow + dx;
                float y = (float)col + dy;
                float x0 = floorf(x), y0 = floorf(y);
                float wx1 = x - x0, wx0 = 1.0f - wx1;
                float wy1 = y - y0, wy0 = 1.0f - wy1;
                int gx0 = ((int)x0) & (H - 1);
                int gx1 = (gx0 + 1) & (H - 1);
                int gy0 = ((int)y0) & (W - 1);
                int gy1 = (gy0 + 1) & (W - 1);
                atomicAdd(outb + (size_t)gx0 * W + gy0, wx0 * wy0);
                atomicAdd(outb + (size_t)gx0 * W + gy1, wx0 * wy1);
                atomicAdd(outb + (size_t)gx1 * W + gy0, wx1 * wy0);
                atomicAdd(outb + (size_t)gx1 * W + gy1, wx1 * wy1);
            }
        }
    }
}

extern "C" void kernel_launch(void* const* d_in, const int* in_sizes, int n_in,
                              void* d_out, int out_size, void* d_ws, size_t ws_size,
                              hipStream_t stream) {
    const float* phi = (const float*)d_in[0];
    float* out = (float*)d_out;
    unsigned char* flags = (unsigned char*)d_ws;   // B*H*NCH bytes, fully rewritten per call

    int B = out_size / HW;
    int grid = B * NCH * (H / ROWSPB);             // 4 * 37 * 64 = 9472 blocks
    splat_gather8o<<<grid, 256, 0, stream>>>(phi, out, flags);

    long long nChunks = (long long)B * H * NCH;    // 303,104 = 4736 * 64
    int grid2 = (int)(nChunks / (WPB * 16));       // 4736 blocks (16 chunks per wave)
    flush_flagged<<<grid2, 256, 0, stream>>>(phi, flags, out);
}